// Round 13
// baseline (198.511 us; speedup 1.0000x reference)
//
#include <hip/hip_runtime.h>

#define HEADS 8
#define Bq 4
#define Nq 2048
#define Dq 512
#define Hq 2048

typedef __bf16 bf16;
typedef __bf16 bf16x8 __attribute__((ext_vector_type(8)));
typedef __bf16 bf16x4 __attribute__((ext_vector_type(4)));
typedef short short4v __attribute__((ext_vector_type(4)));
typedef float f32x4 __attribute__((ext_vector_type(4)));

__device__ __forceinline__ void gload16(const bf16* g, bf16* s) {
  __builtin_amdgcn_global_load_lds(
      (const __attribute__((address_space(1))) void*)g,
      (__attribute__((address_space(3))) void*)s, 16, 0, 0);
}

__device__ __forceinline__ float fexp2(float x) {
#if __has_builtin(__builtin_amdgcn_exp2f)
  return __builtin_amdgcn_exp2f(x);
#else
  return exp2f(x);
#endif
}

// 16x16x16 bf16 MFMA (legacy shape; A/B = 4 bf16 = 2 VGPR, k = 4g..4g+3 per lane)
__device__ __forceinline__ f32x4 mfma16(bf16x4 a, bf16x4 b, f32x4 c) {
#if __has_builtin(__builtin_amdgcn_mfma_f32_16x16x16bf16_1k)
  return __builtin_amdgcn_mfma_f32_16x16x16bf16_1k(
      __builtin_bit_cast(short4v, a), __builtin_bit_cast(short4v, b), c, 0, 0, 0);
#else
  f32x4 d = c;
  asm("v_mfma_f32_16x16x16_bf16 %0, %1, %2, %0" : "+v"(d) : "v"(a), "v"(b));
  return d;
#endif
}

// ---------------- fp32 -> bf16 elementwise convert ----------------
__global__ __launch_bounds__(256) void k_cvt_bf16(const float* __restrict__ in,
                                                  bf16* __restrict__ out, int n) {
  int i = (blockIdx.x * 256 + threadIdx.x) * 4;
  if (i >= n) return;
  float4 v = *(const float4*)(in + i);
  union { bf16 h[4]; ushort4 u; } r;
  r.h[0] = (bf16)v.x; r.h[1] = (bf16)v.y; r.h[2] = (bf16)v.z; r.h[3] = (bf16)v.w;
  *(ushort4*)(out + i) = r.u;
}

// ---------------- transpose + convert: in fp32 [K][N] -> out bf16 [N][K] ----------------
__global__ __launch_bounds__(256) void k_transpose_cvt(const float* __restrict__ in,
                                                       bf16* __restrict__ out,
                                                       int K, int N) {
  __shared__ float t[32][33];
  const int n0 = blockIdx.x * 32, k0 = blockIdx.y * 32;
  const int tx = threadIdx.x, ty = threadIdx.y;
#pragma unroll
  for (int j = 0; j < 32; j += 8)
    t[ty + j][tx] = in[(size_t)(k0 + ty + j) * N + n0 + tx];
  __syncthreads();
#pragma unroll
  for (int j = 0; j < 32; j += 8)
    out[(size_t)(n0 + ty + j) * K + k0 + tx] = (bf16)t[tx][ty + j];
}

// ---------------- GEMM: C[M][N] = A[M][K](bf16) * BT[N][K]^T + bias ----------------
// m97-shape: 256 threads = 4 waves (2x2), BM x 128 tile, MI=NI per-wave frag
// grid, BK=32, 32/24 KB dbuf LDS -> 4 blocks/CU. Chunk-rotation swizzle
// (stored = (logical + ((row&15)>>1)) & 3; inverse on per-lane global source)
// makes staging writes and b128 frag reads 2-way (free). Epilogue bounces C
// through LDS for coalesced 16-B stores (no write-allocate RMW).
template <int BM, bool GELU, bool RESID, bool STORE_BF16>
__global__ __launch_bounds__(256) void k_gemm(const bf16* __restrict__ A,
                                              const bf16* __restrict__ BT,
                                              const float* __restrict__ bias,
                                              const float* __restrict__ resid,
                                              void* __restrict__ Cout,
                                              int M, int N, int K) {
  constexpr int MI = BM / 32;          // M-frags per wave (wave M-span = BM/2)
  constexpr int AI = BM / 64;          // A staging instrs per thread group
  constexpr size_t MAIN = (size_t)2 * (BM + 128) * 32 * 2;
  constexpr size_t CST = (size_t)BM * 136 * (STORE_BF16 ? 2 : 4);
  constexpr size_t SMEM = MAIN > CST ? MAIN : CST;
  __shared__ __align__(16) char smem[SMEM];
  bf16* Asb = (bf16*)smem;                     // [2][BM*32]
  bf16* Bsb = Asb + 2 * BM * 32;               // [2][128*32]

  const int m0 = blockIdx.y * BM, n0 = blockIdx.x * 128;
  const int tid = threadIdx.x, lane = tid & 63, wid = tid >> 6;
  const int wr = wid >> 1, wc = wid & 1;
  const int r16 = lane & 15, g = lane >> 4;
  const int srow = lane >> 2;                  // 0..15 rows within wave-block
  const int sc = ((lane & 3) - ((lane >> 3) & 3)) & 3;  // inverse-swizzled src chunk

  f32x4 acc[MI][4] = {};

  const int NT = K >> 5;
  auto stage = [&](int t, int buf) {
    const int k0 = t << 5;
#pragma unroll
    for (int i = 0; i < AI; i++) {
      int row = i * 64 + wid * 16;
      gload16(A + (size_t)(m0 + row + srow) * K + k0 + sc * 8,
              Asb + buf * BM * 32 + row * 32);
    }
#pragma unroll
    for (int i = 0; i < 2; i++) {
      int row = i * 64 + wid * 16;
      gload16(BT + (size_t)(n0 + row + srow) * K + k0 + sc * 8,
              Bsb + buf * 128 * 32 + row * 32);
    }
  };

  stage(0, 0);
  __syncthreads();

  for (int t = 0; t < NT; t++) {
    const int cur = t & 1;
    if (t + 1 < NT) stage(t + 1, cur ^ 1);
    const bf16* Ab = Asb + cur * BM * 32;
    const bf16* Bb = Bsb + cur * 128 * 32;
    bf16x8 af[MI], bfr[4];
#pragma unroll
    for (int mi = 0; mi < MI; mi++)
      af[mi] = *(const bf16x8*)(Ab + (wr * (BM / 2) + mi * 16 + r16) * 32 +
                                (((g + (r16 >> 1)) & 3) * 8));
#pragma unroll
    for (int ni = 0; ni < 4; ni++)
      bfr[ni] = *(const bf16x8*)(Bb + (wc * 64 + ni * 16 + r16) * 32 +
                                 (((g + (r16 >> 1)) & 3) * 8));
#pragma unroll
    for (int mi = 0; mi < MI; mi++)
#pragma unroll
      for (int ni = 0; ni < 4; ni++)
        acc[mi][ni] = __builtin_amdgcn_mfma_f32_16x16x32_bf16(af[mi], bfr[ni],
                                                              acc[mi][ni], 0, 0, 0);
    __syncthreads();
  }

  // ---- epilogue: acc -> LDS C-tile -> coalesced 16B stores ----
  float bv[4];
#pragma unroll
  for (int ni = 0; ni < 4; ni++) bv[ni] = bias[n0 + wc * 64 + ni * 16 + r16];

  if (STORE_BF16) {
    bf16* Cl = (bf16*)smem;
#pragma unroll
    for (int mi = 0; mi < MI; mi++)
#pragma unroll
      for (int ni = 0; ni < 4; ni++)
#pragma unroll
        for (int r = 0; r < 4; r++) {
          float v = acc[mi][ni][r] + bv[ni];
          if (GELU) v = 0.5f * v * (1.f + erff(v * 0.70710678118654752f));
          Cl[(wr * (BM / 2) + mi * 16 + 4 * g + r) * 136 + wc * 64 + ni * 16 + r16] =
              (bf16)v;
        }
    __syncthreads();
    constexpr int ROWS_PER = 256 * 8 / 128;  // 16
#pragma unroll
    for (int rr = 0; rr < BM / ROWS_PER; rr++) {
      int row = rr * ROWS_PER + (tid >> 4);
      int cc = (tid & 15) * 8;
      bf16x8 v = *(const bf16x8*)(Cl + row * 136 + cc);
      *(bf16x8*)((bf16*)Cout + (size_t)(m0 + row) * N + n0 + cc) = v;
    }
  } else {
    float* Cl = (float*)smem;
#pragma unroll
    for (int mi = 0; mi < MI; mi++)
#pragma unroll
      for (int ni = 0; ni < 4; ni++)
#pragma unroll
        for (int r = 0; r < 4; r++) {
          float v = acc[mi][ni][r] + bv[ni];
          if (GELU) v = 0.5f * v * (1.f + erff(v * 0.70710678118654752f));
          Cl[(wr * (BM / 2) + mi * 16 + 4 * g + r) * 136 + wc * 64 + ni * 16 + r16] = v;
        }
    __syncthreads();
    constexpr int ROWS_PER = 256 * 4 / 128;  // 8
#pragma unroll
    for (int rr = 0; rr < BM / ROWS_PER; rr++) {
      int row = rr * ROWS_PER + (tid >> 5);
      int cc = (tid & 31) * 4;
      f32x4 v = *(const f32x4*)(Cl + row * 136 + cc);
      if (RESID) {
        f32x4 rv = *(const f32x4*)(resid + (size_t)(m0 + row) * N + n0 + cc);
        v += rv;
      }
      *(f32x4*)((float*)Cout + (size_t)(m0 + row) * N + n0 + cc) = v;
    }
  }
}

// ---------------- V transpose+interleave: qkvb V-cols -> vt[B*H][64][Nq] ----------------
__global__ __launch_bounds__(256) void k_vtrans(const bf16* __restrict__ qkv,
                                                bf16* __restrict__ vt) {
  __shared__ bf16 T[64 * 66];
  const int kvb = blockIdx.x, bh = blockIdx.y;
  const int b = bh >> 3, h = bh & 7;
  const int tid = threadIdx.x, lane = tid & 63, w = tid >> 6;
  const bf16* src = qkv + ((size_t)b * Nq + kvb * 64) * (3 * Dq) + 2 * Dq + h * 64;
#pragma unroll
  for (int i = 0; i < 2; i++) {
    int u = tid + i * 256;
    int r = u >> 3, ch = u & 7;
    *(int4*)(&T[r * 66 + ch * 8]) = *(const int4*)(src + (size_t)r * (3 * Dq) + ch * 8);
  }
  __syncthreads();
  const int kvm = 16 * ((lane >> 2) & 3) + 4 * (lane >> 4) + (lane & 3);
  bf16* dst = vt + (size_t)bh * 64 * Nq + kvb * 64 + lane;
#pragma unroll
  for (int it = 0; it < 16; it++) {
    int e = w * 16 + it;
    dst[(size_t)e * Nq] = T[kvm * 66 + e];
  }
}

// ---------------- flash attention: O^T = V^T P^T, no-max exp2 softmax ----------------
// grid (B*H, Nq/64): 4 waves x 16 q-rows (round-11 verified config).
__global__ __launch_bounds__(256) void k_attn(const bf16* __restrict__ qkv,
                                              const bf16* __restrict__ vt,
                                              bf16* __restrict__ att) {
  __shared__ bf16 Ks[2][64 * 64];
  __shared__ bf16 Vs[2][64 * 64];
  const int qt = blockIdx.y, b = blockIdx.x >> 3, h = blockIdx.x & 7;
  const int tid = threadIdx.x, lane = tid & 63, wid = tid >> 6;
  const int r16 = lane & 15, g = lane >> 4;
  const size_t base = (size_t)b * Nq * (3 * Dq);
  const bf16* qp = qkv + base + h * 64;
  const bf16* kp = qkv + base + Dq + h * 64;
  const bf16* vtp = vt + (size_t)(b * HEADS + h) * 64 * Nq;
  const int q0 = qt * 64 + wid * 16;

  // Q frags, pre-scaled by log2(e) -> S in exp2 domain
  bf16x8 qf[2];
#pragma unroll
  for (int kk = 0; kk < 2; kk++) {
    bf16x8 q = *(const bf16x8*)(qp + (size_t)(q0 + r16) * (3 * Dq) + kk * 32 + g * 8);
#pragma unroll
    for (int j = 0; j < 8; j++) q[j] = (bf16)((float)q[j] * 1.44269504f);
    qf[kk] = q;
  }

  const int srow = lane >> 3;
  const int sch = (lane & 7) ^ srow;
  const bf16x4 ones = {(bf16)1.f, (bf16)1.f, (bf16)1.f, (bf16)1.f};

  f32x4 o[4] = {};
  f32x4 ol = {};              // l accumulator (every row = sum over kv of P)

#pragma unroll
  for (int i = 0; i < 2; i++) {
    int br = (wid * 2 + i) * 8;
    gload16(kp + (size_t)(br + srow) * (3 * Dq) + sch * 8, &Ks[0][br * 64]);
    gload16(vtp + (size_t)(br + srow) * Nq + sch * 8, &Vs[0][br * 64]);
  }
  __syncthreads();

  const int NTILES = Nq / 64;
  auto tile = [&](int t, int c) {
    if (t + 1 < NTILES) {
      const int kv1 = (t + 1) * 64;
#pragma unroll
      for (int i = 0; i < 2; i++) {
        int br = (wid * 2 + i) * 8;
        gload16(kp + (size_t)(kv1 + br + srow) * (3 * Dq) + sch * 8,
                &Ks[c ^ 1][br * 64]);
        gload16(vtp + (size_t)(br + srow) * Nq + kv1 + sch * 8, &Vs[c ^ 1][br * 64]);
      }
    }

    // S^T[kv][q]: s[nt]
    f32x4 s[4] = {};
#pragma unroll
    for (int kk = 0; kk < 2; kk++)
#pragma unroll
      for (int nt = 0; nt < 4; nt++) {
        const bf16x8 kf = *(const bf16x8*)(
            &Ks[c][(nt * 16 + r16) * 64 + (((4 * kk + g) ^ (r16 & 7)) * 8)]);
        s[nt] = __builtin_amdgcn_mfma_f32_16x16x32_bf16(kf, qf[kk], s[nt], 0, 0, 0);
      }

    // no-max softmax: P = 2^s directly (range-safe; O/l cancels the constant)
#pragma unroll
    for (int nt = 0; nt < 4; nt++)
#pragma unroll
      for (int r = 0; r < 4; r++) s[nt][r] = fexp2(s[nt][r]);

    // pack P^T to bf16: pk[s4] IS the 16x16x16 B-frag (k=4g+j, col=r16)
    bf16x4 pk[4];
#pragma unroll
    for (int s4 = 0; s4 < 4; s4++) {
      bf16x4 p;
#pragma unroll
      for (int j = 0; j < 4; j++) p[j] = (bf16)s[s4][j];
      pk[s4] = p;
    }

    // l via MFMA: every row of ol += column-sums of this tile's P
    ol = mfma16(ones, pk[0], ol);
    ol = mfma16(ones, pk[1], ol);
    ol = mfma16(ones, pk[2], ol);
    ol = mfma16(ones, pk[3], ol);

    // PV: O^T[e][q] += V^T A-frags x P^T B-frags, 4 steps of k=16
#pragma unroll
    for (int ot = 0; ot < 4; ot++) {
      const int row = ot * 16 + r16;
      const bf16x8 vf0 = *(const bf16x8*)(
          &Vs[c][row * 64 + (((2 * g + 0) ^ (r16 & 7)) * 8)]);
      const bf16x8 vf1 = *(const bf16x8*)(
          &Vs[c][row * 64 + (((2 * g + 1) ^ (r16 & 7)) * 8)]);
      const bf16x4 a0 = __builtin_shufflevector(vf0, vf0, 0, 1, 2, 3);
      const bf16x4 a1 = __builtin_shufflevector(vf0, vf0, 4, 5, 6, 7);
      const bf16x4 a2 = __builtin_shufflevector(vf1, vf1, 0, 1, 2, 3);
      const bf16x4 a3 = __builtin_shufflevector(vf1, vf1, 4, 5, 6, 7);
      o[ot] = mfma16(a0, pk[0], o[ot]);
      o[ot] = mfma16(a1, pk[1], o[ot]);
      o[ot] = mfma16(a2, pk[2], o[ot]);
      o[ot] = mfma16(a3, pk[3], o[ot]);
    }
    __syncthreads();
  };

  for (int t = 0; t < NTILES; t += 2) {
    tile(t, 0);
    tile(t + 1, 1);
  }

  asm volatile("s_nop 7\ns_nop 7");  // MFMA->VALU hazard guard before epilogue

  // epilogue: O^T col=q=r16 (same lane as l), row e = ot*16+4g+r
  const float li = 0.125f / ol[0];
  const size_t rowoff = ((size_t)b * Nq + q0 + r16) * Dq + h * 64;
#pragma unroll
  for (int ot = 0; ot < 4; ot++) {
    union { bf16 h[4]; ushort4 u; } r4;
#pragma unroll
    for (int r = 0; r < 4; r++) r4.h[r] = (bf16)(o[ot][r] * li);
    *(ushort4*)(att + rowoff + ot * 16 + 4 * g) = r4.u;
  }
}

// ---------------- LayerNorm over D=512, one wave per row ----------------
template <bool WB>
__global__ __launch_bounds__(64) void k_ln(const float* __restrict__ in,
                                           const float* __restrict__ gamma,
                                           const float* __restrict__ beta,
                                           float* __restrict__ outf,
                                           bf16* __restrict__ outb) {
  const int row = blockIdx.x, lane = threadIdx.x;
  const float* p = in + (size_t)row * Dq + lane * 8;
  float4 a = *(const float4*)p;
  float4 c = *(const float4*)(p + 4);
  float vals[8] = {a.x, a.y, a.z, a.w, c.x, c.y, c.z, c.w};
  float s = 0.f, q = 0.f;
#pragma unroll
  for (int j = 0; j < 8; j++) { s += vals[j]; q += vals[j] * vals[j]; }
#pragma unroll
  for (int off = 1; off < 64; off <<= 1) {
    s += __shfl_xor(s, off);
    q += __shfl_xor(q, off);
  }
  float mean = s * (1.f / Dq);
  float var = q * (1.f / Dq) - mean * mean;
  float rstd = rsqrtf(var + 1e-5f);
  float of[8];
#pragma unroll
  for (int j = 0; j < 8; j++) {
    int col = lane * 8 + j;
    of[j] = (vals[j] - mean) * rstd * gamma[col] + beta[col];
  }
  float4* op = (float4*)(outf + (size_t)row * Dq + lane * 8);
  op[0] = make_float4(of[0], of[1], of[2], of[3]);
  op[1] = make_float4(of[4], of[5], of[6], of[7]);
  if (WB) {
    union { bf16 h[8]; ushort4 u[2]; } rr;
#pragma unroll
    for (int j = 0; j < 8; j++) rr.h[j] = (bf16)of[j];
    ushort4* ob = (ushort4*)(outb + (size_t)row * Dq + lane * 8);
    ob[0] = rr.u[0];
    ob[1] = rr.u[1];
  }
}

extern "C" void kernel_launch(void* const* d_in, const int* in_sizes, int n_in,
                              void* d_out, int out_size, void* d_ws, size_t ws_size,
                              hipStream_t stream) {
  const float* x      = (const float*)d_in[0];
  const float* w_qkv  = (const float*)d_in[1];
  const float* b_qkv  = (const float*)d_in[2];
  const float* w_proj = (const float*)d_in[3];
  const float* b_proj = (const float*)d_in[4];
  const float* ln1_g  = (const float*)d_in[5];
  const float* ln1_b  = (const float*)d_in[6];
  const float* w1     = (const float*)d_in[7];
  const float* b1     = (const float*)d_in[8];
  const float* w2     = (const float*)d_in[9];
  const float* b2     = (const float*)d_in[10];
  const float* ln2_g  = (const float*)d_in[11];
  const float* ln2_b  = (const float*)d_in[12];
  float* out = (float*)d_out;

  const int M = Bq * Nq;  // 8192 rows

  char* p = (char*)d_ws;
  auto alloc = [&](size_t bytes) -> void* {
    char* r = p;
    p += (bytes + 255) & ~(size_t)255;
    return (void*)r;
  };
  bf16* xb     = (bf16*)alloc((size_t)M * Dq * 2);        // x bf16; later reused as att
  bf16* qkvb   = (bf16*)alloc((size_t)M * 3 * Dq * 2);
  bf16* wqkvT  = (bf16*)alloc((size_t)3 * Dq * Dq * 2);
  bf16* wprojT = (bf16*)alloc((size_t)Dq * Dq * 2);
  bf16* w1T    = (bf16*)alloc((size_t)Hq * Dq * 2);
  bf16* w2T    = (bf16*)alloc((size_t)Dq * Hq * 2);
  float* y1    = (float*)alloc((size_t)M * Dq * 4);       // also y2
  float* x1f   = (float*)alloc((size_t)M * Dq * 4);
  bf16* x1b    = (bf16*)alloc((size_t)M * Dq * 2);
  bf16* hb     = (bf16*)alloc((size_t)M * Hq * 2);
  bf16* attb   = xb;   // alias: xb consumed by qkv GEMM before attention writes
  bf16* vtb    = hb;   // alias: hb written by ffn1 only after attention is done

  dim3 tb(32, 8);
  k_cvt_bf16<<<(M * Dq / 4 + 255) / 256, 256, 0, stream>>>(x, xb, M * Dq);
  k_transpose_cvt<<<dim3((3 * Dq) / 32, Dq / 32), tb, 0, stream>>>(w_qkv, wqkvT, Dq, 3 * Dq);
  k_transpose_cvt<<<dim3(Dq / 32, Dq / 32), tb, 0, stream>>>(w_proj, wprojT, Dq, Dq);
  k_transpose_cvt<<<dim3(Hq / 32, Dq / 32), tb, 0, stream>>>(w1, w1T, Dq, Hq);
  k_transpose_cvt<<<dim3(Dq / 32, Hq / 32), tb, 0, stream>>>(w2, w2T, Hq, Dq);

  // qkv = x @ w_qkv + b_qkv
  k_gemm<128, false, false, true><<<dim3((3 * Dq) / 128, M / 128), 256, 0, stream>>>(
      xb, wqkvT, b_qkv, nullptr, qkvb, M, 3 * Dq, Dq);
  // vt = transpose+interleave of V part
  k_vtrans<<<dim3(Nq / 64, Bq * HEADS), 256, 0, stream>>>(qkvb, vtb);
  // attention (QBLK=64: 1024 blocks, 4 blocks/CU)
  k_attn<<<dim3(Bq * HEADS, Nq / 64), 256, 0, stream>>>(qkvb, vtb, attb);
  // y1 = att @ w_proj + b_proj + x
  k_gemm<64, false, true, false><<<dim3(Dq / 128, M / 64), 256, 0, stream>>>(
      attb, wprojT, b_proj, x, y1, M, Dq, Dq);
  // x1 = LN1(y1) -> fp32 + bf16
  k_ln<true><<<M, 64, 0, stream>>>(y1, ln1_g, ln1_b, x1f, x1b);
  // h = gelu(x1 @ w1 + b1)
  k_gemm<128, true, false, true><<<dim3(Hq / 128, M / 128), 256, 0, stream>>>(
      x1b, w1T, b1, nullptr, hb, M, Hq, Dq);
  // y2 = h @ w2 + b2 + x1
  k_gemm<64, false, true, false><<<dim3(Dq / 128, M / 64), 256, 0, stream>>>(
      hb, w2T, b2, x1f, y1, M, Dq, Hq);
  // out = LN2(y2)
  k_ln<false><<<M, 64, 0, stream>>>(y1, ln2_g, ln2_b, out, nullptr);
}

// Round 14
// 185.914 us; speedup vs baseline: 1.0678x; 1.0678x over previous
//
#include <hip/hip_runtime.h>

#define HEADS 8
#define Bq 4
#define Nq 2048
#define Dq 512
#define Hq 2048

typedef __bf16 bf16;
typedef __bf16 bf16x8 __attribute__((ext_vector_type(8)));
typedef __bf16 bf16x4 __attribute__((ext_vector_type(4)));
typedef short short4v __attribute__((ext_vector_type(4)));
typedef float f32x4 __attribute__((ext_vector_type(4)));

__device__ __forceinline__ void gload16(const bf16* g, bf16* s) {
  __builtin_amdgcn_global_load_lds(
      (const __attribute__((address_space(1))) void*)g,
      (__attribute__((address_space(3))) void*)s, 16, 0, 0);
}

__device__ __forceinline__ float fexp2(float x) {
#if __has_builtin(__builtin_amdgcn_exp2f)
  return __builtin_amdgcn_exp2f(x);
#else
  return exp2f(x);
#endif
}

// 16x16x16 bf16 MFMA (legacy shape; A/B = 4 bf16 = 2 VGPR, k = 4g..4g+3 per lane)
__device__ __forceinline__ f32x4 mfma16(bf16x4 a, bf16x4 b, f32x4 c) {
#if __has_builtin(__builtin_amdgcn_mfma_f32_16x16x16bf16_1k)
  return __builtin_amdgcn_mfma_f32_16x16x16bf16_1k(
      __builtin_bit_cast(short4v, a), __builtin_bit_cast(short4v, b), c, 0, 0, 0);
#else
  f32x4 d = c;
  asm("v_mfma_f32_16x16x16_bf16 %0, %1, %2, %0" : "+v"(d) : "v"(a), "v"(b));
  return d;
#endif
}

// counted-vmcnt barrier pair helpers (T4): confirm own older loads done, then
// collective barrier -> all waves' older loads done; newly-issued stay in flight.
#define VM_BARRIER(N)                                         \
  do {                                                        \
    asm volatile("s_waitcnt vmcnt(" #N ")" ::: "memory");     \
    __builtin_amdgcn_s_barrier();                             \
    asm volatile("" ::: "memory");                            \
  } while (0)
#define END_BARRIER()                                         \
  do {                                                        \
    asm volatile("" ::: "memory");                            \
    __builtin_amdgcn_s_barrier();                             \
    asm volatile("" ::: "memory");                            \
  } while (0)

// ---------------- fp32 -> bf16 elementwise convert ----------------
__global__ __launch_bounds__(256) void k_cvt_bf16(const float* __restrict__ in,
                                                  bf16* __restrict__ out, int n) {
  int i = (blockIdx.x * 256 + threadIdx.x) * 4;
  if (i >= n) return;
  float4 v = *(const float4*)(in + i);
  union { bf16 h[4]; ushort4 u; } r;
  r.h[0] = (bf16)v.x; r.h[1] = (bf16)v.y; r.h[2] = (bf16)v.z; r.h[3] = (bf16)v.w;
  *(ushort4*)(out + i) = r.u;
}

// ---------------- transpose + convert: in fp32 [K][N] -> out bf16 [N][K] ----------------
__global__ __launch_bounds__(256) void k_transpose_cvt(const float* __restrict__ in,
                                                       bf16* __restrict__ out,
                                                       int K, int N) {
  __shared__ float t[32][33];
  const int n0 = blockIdx.x * 32, k0 = blockIdx.y * 32;
  const int tx = threadIdx.x, ty = threadIdx.y;
#pragma unroll
  for (int j = 0; j < 32; j += 8)
    t[ty + j][tx] = in[(size_t)(k0 + ty + j) * N + n0 + tx];
  __syncthreads();
#pragma unroll
  for (int j = 0; j < 32; j += 8)
    out[(size_t)(n0 + ty + j) * K + k0 + tx] = (bf16)t[tx][ty + j];
}

// ---------------- GEMM: C[M][N] = A[M][K](bf16) * BT[N][K]^T + bias ----------------
// BM x 128 tile, BK=64, 512 threads = 8 waves (2 wr x 4 wc). global_load_lds
// width-16 staging, double-buffered, XOR-swizzled b128 frag reads. K-loop uses
// counted-vmcnt two-barrier schedule (no vmcnt(0) drain in steady state):
//   stage(t+1) -> vmcnt(G) -> barrier -> compute(t) -> barrier.
// Epilogue bounces C through LDS for coalesced 16-B stores.
template <int BM, bool GELU, bool RESID, bool STORE_BF16>
__global__ __launch_bounds__(512, 4) void k_gemm(const bf16* __restrict__ A,
                                                 const bf16* __restrict__ BT,
                                                 const float* __restrict__ bias,
                                                 const float* __restrict__ resid,
                                                 void* __restrict__ Cout,
                                                 int M, int N, int K) {
  constexpr int MI = BM / 32;          // M-frags per wave (wave M-span = BM/2)
  constexpr int AROUNDS = BM / 64;     // 512-thr staging rounds for A
  constexpr size_t MAIN = (size_t)2 * (BM + 128) * 64 * 2;
  constexpr size_t CST = (size_t)BM * 136 * (STORE_BF16 ? 2 : 4);
  constexpr size_t SMEM = MAIN > CST ? MAIN : CST;
  __shared__ __align__(16) char smem[SMEM];
  bf16* Asb = (bf16*)smem;                     // [2][BM*64]
  bf16* Bsb = Asb + 2 * BM * 64;               // [2][128*64]

  const int m0 = blockIdx.y * BM, n0 = blockIdx.x * 128;
  const int tid = threadIdx.x, lane = tid & 63, wid = tid >> 6;
  const int wr = wid >> 2, wc = wid & 3;
  const int r16 = lane & 15, g = lane >> 4;
  const int lrow = lane >> 3;                  // 0..7 rows within a gload round
  const int sch = (lane & 7) ^ lrow;           // inverse-swizzled source chunk

  f32x4 acc[MI][2] = {};

  const int NT = K >> 6;
  auto stage = [&](int t, int buf) {
    const int k0 = t << 6;
#pragma unroll
    for (int i = 0; i < AROUNDS; i++) {
      int row = i * 64 + wid * 8 + lrow;
      gload16(A + (size_t)(m0 + row) * K + k0 + sch * 8,
              Asb + buf * BM * 64 + (i * 64 + wid * 8) * 64);
    }
#pragma unroll
    for (int i = 0; i < 2; i++) {
      int row = i * 64 + wid * 8 + lrow;
      gload16(BT + (size_t)(n0 + row) * K + k0 + sch * 8,
              Bsb + buf * 128 * 64 + (i * 64 + wid * 8) * 64);
    }
  };

  stage(0, 0);

  for (int t = 0; t < NT; t++) {
    const int cur = t & 1;
    if (t + 1 < NT) {
      stage(t + 1, cur ^ 1);
      if constexpr (AROUNDS == 2) VM_BARRIER(4);
      else                        VM_BARRIER(3);
    } else {
      VM_BARRIER(0);
    }
    const bf16* Ab = Asb + cur * BM * 64;
    const bf16* Bb = Bsb + cur * 128 * 64;
#pragma unroll
    for (int kk = 0; kk < 2; kk++) {
      bf16x8 af[MI], bfr[2];
#pragma unroll
      for (int mi = 0; mi < MI; mi++)
        af[mi] = *(const bf16x8*)(Ab + (wr * (BM / 2) + mi * 16 + r16) * 64 +
                                  (((kk * 4 + g) ^ (r16 & 7)) * 8));
#pragma unroll
      for (int ni = 0; ni < 2; ni++)
        bfr[ni] = *(const bf16x8*)(Bb + (wc * 32 + ni * 16 + r16) * 64 +
                                   (((kk * 4 + g) ^ (r16 & 7)) * 8));
#pragma unroll
      for (int mi = 0; mi < MI; mi++)
#pragma unroll
        for (int ni = 0; ni < 2; ni++)
          acc[mi][ni] = __builtin_amdgcn_mfma_f32_16x16x32_bf16(af[mi], bfr[ni],
                                                                acc[mi][ni], 0, 0, 0);
    }
    END_BARRIER();
  }

  // ---- epilogue: acc -> LDS C-tile -> coalesced 16B stores ----
  float bv[2];
#pragma unroll
  for (int ni = 0; ni < 2; ni++) bv[ni] = bias[n0 + wc * 32 + ni * 16 + r16];

  if (STORE_BF16) {
    bf16* Cl = (bf16*)smem;
#pragma unroll
    for (int mi = 0; mi < MI; mi++)
#pragma unroll
      for (int ni = 0; ni < 2; ni++)
#pragma unroll
        for (int r = 0; r < 4; r++) {
          float v = acc[mi][ni][r] + bv[ni];
          if (GELU) v = 0.5f * v * (1.f + erff(v * 0.70710678118654752f));
          Cl[(wr * (BM / 2) + mi * 16 + 4 * g + r) * 136 + wc * 32 + ni * 16 + r16] =
              (bf16)v;
        }
    __syncthreads();
    constexpr int ROWS_PER = 512 * 8 / 128;  // 32
#pragma unroll
    for (int rr = 0; rr < BM / ROWS_PER; rr++) {
      int row = rr * ROWS_PER + (tid >> 4);
      int cc = (tid & 15) * 8;
      bf16x8 v = *(const bf16x8*)(Cl + row * 136 + cc);
      *(bf16x8*)((bf16*)Cout + (size_t)(m0 + row) * N + n0 + cc) = v;
    }
  } else {
    float* Cl = (float*)smem;
#pragma unroll
    for (int mi = 0; mi < MI; mi++)
#pragma unroll
      for (int ni = 0; ni < 2; ni++)
#pragma unroll
        for (int r = 0; r < 4; r++) {
          float v = acc[mi][ni][r] + bv[ni];
          if (GELU) v = 0.5f * v * (1.f + erff(v * 0.70710678118654752f));
          Cl[(wr * (BM / 2) + mi * 16 + 4 * g + r) * 136 + wc * 32 + ni * 16 + r16] = v;
        }
    __syncthreads();
    constexpr int ROWS_PER = 512 * 4 / 128;  // 16
#pragma unroll
    for (int rr = 0; rr < BM / ROWS_PER; rr++) {
      int row = rr * ROWS_PER + (tid >> 5);
      int cc = (tid & 31) * 4;
      f32x4 v = *(const f32x4*)(Cl + row * 136 + cc);
      if (RESID) {
        f32x4 rv = *(const f32x4*)(resid + (size_t)(m0 + row) * N + n0 + cc);
        v += rv;
      }
      *(f32x4*)((float*)Cout + (size_t)(m0 + row) * N + n0 + cc) = v;
    }
  }
}

// ---------------- V transpose+interleave: qkvb V-cols -> vt[B*H][64][Nq] ----------------
__global__ __launch_bounds__(256) void k_vtrans(const bf16* __restrict__ qkv,
                                                bf16* __restrict__ vt) {
  __shared__ bf16 T[64 * 66];
  const int kvb = blockIdx.x, bh = blockIdx.y;
  const int b = bh >> 3, h = bh & 7;
  const int tid = threadIdx.x, lane = tid & 63, w = tid >> 6;
  const bf16* src = qkv + ((size_t)b * Nq + kvb * 64) * (3 * Dq) + 2 * Dq + h * 64;
#pragma unroll
  for (int i = 0; i < 2; i++) {
    int u = tid + i * 256;
    int r = u >> 3, ch = u & 7;
    *(int4*)(&T[r * 66 + ch * 8]) = *(const int4*)(src + (size_t)r * (3 * Dq) + ch * 8);
  }
  __syncthreads();
  const int kvm = 16 * ((lane >> 2) & 3) + 4 * (lane >> 4) + (lane & 3);
  bf16* dst = vt + (size_t)bh * 64 * Nq + kvb * 64 + lane;
#pragma unroll
  for (int it = 0; it < 16; it++) {
    int e = w * 16 + it;
    dst[(size_t)e * Nq] = T[kvm * 66 + e];
  }
}

// ---------------- flash attention: O^T = V^T P^T, no-max exp2 softmax ----------------
// grid (B*H, Nq/64): 4 waves x 16 q-rows (round-11 config) + counted-vmcnt
// two-barrier tile schedule (prefetch stays in flight through compute).
__global__ __launch_bounds__(256) void k_attn(const bf16* __restrict__ qkv,
                                              const bf16* __restrict__ vt,
                                              bf16* __restrict__ att) {
  __shared__ bf16 Ks[2][64 * 64];
  __shared__ bf16 Vs[2][64 * 64];
  const int qt = blockIdx.y, b = blockIdx.x >> 3, h = blockIdx.x & 7;
  const int tid = threadIdx.x, lane = tid & 63, wid = tid >> 6;
  const int r16 = lane & 15, g = lane >> 4;
  const size_t base = (size_t)b * Nq * (3 * Dq);
  const bf16* qp = qkv + base + h * 64;
  const bf16* kp = qkv + base + Dq + h * 64;
  const bf16* vtp = vt + (size_t)(b * HEADS + h) * 64 * Nq;
  const int q0 = qt * 64 + wid * 16;

  // Q frags, pre-scaled by log2(e) -> S in exp2 domain
  bf16x8 qf[2];
#pragma unroll
  for (int kk = 0; kk < 2; kk++) {
    bf16x8 q = *(const bf16x8*)(qp + (size_t)(q0 + r16) * (3 * Dq) + kk * 32 + g * 8);
#pragma unroll
    for (int j = 0; j < 8; j++) q[j] = (bf16)((float)q[j] * 1.44269504f);
    qf[kk] = q;
  }

  const int srow = lane >> 3;
  const int sch = (lane & 7) ^ srow;
  const bf16x4 ones = {(bf16)1.f, (bf16)1.f, (bf16)1.f, (bf16)1.f};

  f32x4 o[4] = {};
  f32x4 ol = {};              // l accumulator (every row = sum over kv of P)

#pragma unroll
  for (int i = 0; i < 2; i++) {
    int br = (wid * 2 + i) * 8;
    gload16(kp + (size_t)(br + srow) * (3 * Dq) + sch * 8, &Ks[0][br * 64]);
    gload16(vtp + (size_t)(br + srow) * Nq + sch * 8, &Vs[0][br * 64]);
  }
  __syncthreads();  // drains Q loads + stage(0)

  const int NTILES = Nq / 64;
  auto tile = [&](int t, int c) {
    if (t + 1 < NTILES) {
      const int kv1 = (t + 1) * 64;
#pragma unroll
      for (int i = 0; i < 2; i++) {
        int br = (wid * 2 + i) * 8;
        gload16(kp + (size_t)(kv1 + br + srow) * (3 * Dq) + sch * 8,
                &Ks[c ^ 1][br * 64]);
        gload16(vtp + (size_t)(br + srow) * Nq + kv1 + sch * 8, &Vs[c ^ 1][br * 64]);
      }
      VM_BARRIER(4);
    } else {
      VM_BARRIER(0);
    }

    // S^T[kv][q]: s[nt]
    f32x4 s[4] = {};
#pragma unroll
    for (int kk = 0; kk < 2; kk++)
#pragma unroll
      for (int nt = 0; nt < 4; nt++) {
        const bf16x8 kf = *(const bf16x8*)(
            &Ks[c][(nt * 16 + r16) * 64 + (((4 * kk + g) ^ (r16 & 7)) * 8)]);
        s[nt] = __builtin_amdgcn_mfma_f32_16x16x32_bf16(kf, qf[kk], s[nt], 0, 0, 0);
      }

    // no-max softmax: P = 2^s directly (range-safe; O/l cancels the constant)
#pragma unroll
    for (int nt = 0; nt < 4; nt++)
#pragma unroll
      for (int r = 0; r < 4; r++) s[nt][r] = fexp2(s[nt][r]);

    // pack P^T to bf16: pk[s4] IS the 16x16x16 B-frag (k=4g+j, col=r16)
    bf16x4 pk[4];
#pragma unroll
    for (int s4 = 0; s4 < 4; s4++) {
      bf16x4 p;
#pragma unroll
      for (int j = 0; j < 4; j++) p[j] = (bf16)s[s4][j];
      pk[s4] = p;
    }

    // l via MFMA: every row of ol += column-sums of this tile's P
    ol = mfma16(ones, pk[0], ol);
    ol = mfma16(ones, pk[1], ol);
    ol = mfma16(ones, pk[2], ol);
    ol = mfma16(ones, pk[3], ol);

    // PV: O^T[e][q] += V^T A-frags x P^T B-frags, 4 steps of k=16
#pragma unroll
    for (int ot = 0; ot < 4; ot++) {
      const int row = ot * 16 + r16;
      const bf16x8 vf0 = *(const bf16x8*)(
          &Vs[c][row * 64 + (((2 * g + 0) ^ (r16 & 7)) * 8)]);
      const bf16x8 vf1 = *(const bf16x8*)(
          &Vs[c][row * 64 + (((2 * g + 1) ^ (r16 & 7)) * 8)]);
      const bf16x4 a0 = __builtin_shufflevector(vf0, vf0, 0, 1, 2, 3);
      const bf16x4 a1 = __builtin_shufflevector(vf0, vf0, 4, 5, 6, 7);
      const bf16x4 a2 = __builtin_shufflevector(vf1, vf1, 0, 1, 2, 3);
      const bf16x4 a3 = __builtin_shufflevector(vf1, vf1, 4, 5, 6, 7);
      o[ot] = mfma16(a0, pk[0], o[ot]);
      o[ot] = mfma16(a1, pk[1], o[ot]);
      o[ot] = mfma16(a2, pk[2], o[ot]);
      o[ot] = mfma16(a3, pk[3], o[ot]);
    }
    END_BARRIER();
  };

  for (int t = 0; t < NTILES; t += 2) {
    tile(t, 0);
    tile(t + 1, 1);
  }

  asm volatile("s_nop 7\ns_nop 7");  // MFMA->VALU hazard guard before epilogue

  // epilogue: O^T col=q=r16 (same lane as l), row e = ot*16+4g+r
  const float li = 0.125f / ol[0];
  const size_t rowoff = ((size_t)b * Nq + q0 + r16) * Dq + h * 64;
#pragma unroll
  for (int ot = 0; ot < 4; ot++) {
    union { bf16 h[4]; ushort4 u; } r4;
#pragma unroll
    for (int r = 0; r < 4; r++) r4.h[r] = (bf16)(o[ot][r] * li);
    *(ushort4*)(att + rowoff + ot * 16 + 4 * g) = r4.u;
  }
}

// ---------------- LayerNorm over D=512, one wave per row ----------------
template <bool WB>
__global__ __launch_bounds__(64) void k_ln(const float* __restrict__ in,
                                           const float* __restrict__ gamma,
                                           const float* __restrict__ beta,
                                           float* __restrict__ outf,
                                           bf16* __restrict__ outb) {
  const int row = blockIdx.x, lane = threadIdx.x;
  const float* p = in + (size_t)row * Dq + lane * 8;
  float4 a = *(const float4*)p;
  float4 c = *(const float4*)(p + 4);
  float vals[8] = {a.x, a.y, a.z, a.w, c.x, c.y, c.z, c.w};
  float s = 0.f, q = 0.f;
#pragma unroll
  for (int j = 0; j < 8; j++) { s += vals[j]; q += vals[j] * vals[j]; }
#pragma unroll
  for (int off = 1; off < 64; off <<= 1) {
    s += __shfl_xor(s, off);
    q += __shfl_xor(q, off);
  }
  float mean = s * (1.f / Dq);
  float var = q * (1.f / Dq) - mean * mean;
  float rstd = rsqrtf(var + 1e-5f);
  float of[8];
#pragma unroll
  for (int j = 0; j < 8; j++) {
    int col = lane * 8 + j;
    of[j] = (vals[j] - mean) * rstd * gamma[col] + beta[col];
  }
  float4* op = (float4*)(outf + (size_t)row * Dq + lane * 8);
  op[0] = make_float4(of[0], of[1], of[2], of[3]);
  op[1] = make_float4(of[4], of[5], of[6], of[7]);
  if (WB) {
    union { bf16 h[8]; ushort4 u[2]; } rr;
#pragma unroll
    for (int j = 0; j < 8; j++) rr.h[j] = (bf16)of[j];
    ushort4* ob = (ushort4*)(outb + (size_t)row * Dq + lane * 8);
    ob[0] = rr.u[0];
    ob[1] = rr.u[1];
  }
}

extern "C" void kernel_launch(void* const* d_in, const int* in_sizes, int n_in,
                              void* d_out, int out_size, void* d_ws, size_t ws_size,
                              hipStream_t stream) {
  const float* x      = (const float*)d_in[0];
  const float* w_qkv  = (const float*)d_in[1];
  const float* b_qkv  = (const float*)d_in[2];
  const float* w_proj = (const float*)d_in[3];
  const float* b_proj = (const float*)d_in[4];
  const float* ln1_g  = (const float*)d_in[5];
  const float* ln1_b  = (const float*)d_in[6];
  const float* w1     = (const float*)d_in[7];
  const float* b1     = (const float*)d_in[8];
  const float* w2     = (const float*)d_in[9];
  const float* b2     = (const float*)d_in[10];
  const float* ln2_g  = (const float*)d_in[11];
  const float* ln2_b  = (const float*)d_in[12];
  float* out = (float*)d_out;

  const int M = Bq * Nq;  // 8192 rows

  char* p = (char*)d_ws;
  auto alloc = [&](size_t bytes) -> void* {
    char* r = p;
    p += (bytes + 255) & ~(size_t)255;
    return (void*)r;
  };
  bf16* xb     = (bf16*)alloc((size_t)M * Dq * 2);        // x bf16; later reused as att
  bf16* qkvb   = (bf16*)alloc((size_t)M * 3 * Dq * 2);
  bf16* wqkvT  = (bf16*)alloc((size_t)3 * Dq * Dq * 2);
  bf16* wprojT = (bf16*)alloc((size_t)Dq * Dq * 2);
  bf16* w1T    = (bf16*)alloc((size_t)Hq * Dq * 2);
  bf16* w2T    = (bf16*)alloc((size_t)Dq * Hq * 2);
  float* y1    = (float*)alloc((size_t)M * Dq * 4);       // also y2
  float* x1f   = (float*)alloc((size_t)M * Dq * 4);
  bf16* x1b    = (bf16*)alloc((size_t)M * Dq * 2);
  bf16* hb     = (bf16*)alloc((size_t)M * Hq * 2);
  bf16* attb   = xb;   // alias: xb consumed by qkv GEMM before attention writes
  bf16* vtb    = hb;   // alias: hb written by ffn1 only after attention is done

  dim3 tb(32, 8);
  k_cvt_bf16<<<(M * Dq / 4 + 255) / 256, 256, 0, stream>>>(x, xb, M * Dq);
  k_transpose_cvt<<<dim3((3 * Dq) / 32, Dq / 32), tb, 0, stream>>>(w_qkv, wqkvT, Dq, 3 * Dq);
  k_transpose_cvt<<<dim3(Dq / 32, Dq / 32), tb, 0, stream>>>(w_proj, wprojT, Dq, Dq);
  k_transpose_cvt<<<dim3(Hq / 32, Dq / 32), tb, 0, stream>>>(w1, w1T, Dq, Hq);
  k_transpose_cvt<<<dim3(Dq / 32, Hq / 32), tb, 0, stream>>>(w2, w2T, Hq, Dq);

  // qkv = x @ w_qkv + b_qkv
  k_gemm<128, false, false, true><<<dim3((3 * Dq) / 128, M / 128), 512, 0, stream>>>(
      xb, wqkvT, b_qkv, nullptr, qkvb, M, 3 * Dq, Dq);
  // vt = transpose+interleave of V part
  k_vtrans<<<dim3(Nq / 64, Bq * HEADS), 256, 0, stream>>>(qkvb, vtb);
  // attention (QBLK=64: 1024 blocks, 4 blocks/CU)
  k_attn<<<dim3(Bq * HEADS, Nq / 64), 256, 0, stream>>>(qkvb, vtb, attb);
  // y1 = att @ w_proj + b_proj + x
  k_gemm<64, false, true, false><<<dim3(Dq / 128, M / 64), 512, 0, stream>>>(
      attb, wprojT, b_proj, x, y1, M, Dq, Dq);
  // x1 = LN1(y1) -> fp32 + bf16
  k_ln<true><<<M, 64, 0, stream>>>(y1, ln1_g, ln1_b, x1f, x1b);
  // h = gelu(x1 @ w1 + b1)
  k_gemm<128, true, false, true><<<dim3(Hq / 128, M / 128), 512, 0, stream>>>(
      x1b, w1T, b1, nullptr, hb, M, Hq, Dq);
  // y2 = h @ w2 + b2 + x1
  k_gemm<64, false, true, false><<<dim3(Dq / 128, M / 64), 512, 0, stream>>>(
      hb, w2T, b2, x1f, y1, M, Dq, Hq);
  // out = LN2(y2)
  k_ln<false><<<M, 64, 0, stream>>>(y1, ln2_g, ln2_b, out, nullptr);
}

// Round 15
// 179.293 us; speedup vs baseline: 1.1072x; 1.0369x over previous
//
#include <hip/hip_runtime.h>

#define HEADS 8
#define Bq 4
#define Nq 2048
#define Dq 512
#define Hq 2048

typedef __bf16 bf16;
typedef __bf16 bf16x8 __attribute__((ext_vector_type(8)));
typedef __bf16 bf16x4 __attribute__((ext_vector_type(4)));
typedef short short4v __attribute__((ext_vector_type(4)));
typedef float f32x4 __attribute__((ext_vector_type(4)));

__device__ __forceinline__ void gload16(const bf16* g, bf16* s) {
  __builtin_amdgcn_global_load_lds(
      (const __attribute__((address_space(1))) void*)g,
      (__attribute__((address_space(3))) void*)s, 16, 0, 0);
}

__device__ __forceinline__ float fexp2(float x) {
#if __has_builtin(__builtin_amdgcn_exp2f)
  return __builtin_amdgcn_exp2f(x);
#else
  return exp2f(x);
#endif
}

// 16x16x16 bf16 MFMA (legacy shape; A/B = 4 bf16 = 2 VGPR, k = 4g..4g+3 per lane)
__device__ __forceinline__ f32x4 mfma16(bf16x4 a, bf16x4 b, f32x4 c) {
#if __has_builtin(__builtin_amdgcn_mfma_f32_16x16x16bf16_1k)
  return __builtin_amdgcn_mfma_f32_16x16x16bf16_1k(
      __builtin_bit_cast(short4v, a), __builtin_bit_cast(short4v, b), c, 0, 0, 0);
#else
  f32x4 d = c;
  asm("v_mfma_f32_16x16x16_bf16 %0, %1, %2, %0" : "+v"(d) : "v"(a), "v"(b));
  return d;
#endif
}

// counted-vmcnt barrier pair (attn only — helps there, hurts GEMM per R14 A/B)
#define VM_BARRIER(N)                                         \
  do {                                                        \
    asm volatile("s_waitcnt vmcnt(" #N ")" ::: "memory");     \
    __builtin_amdgcn_s_barrier();                             \
    asm volatile("" ::: "memory");                            \
  } while (0)
#define END_BARRIER()                                         \
  do {                                                        \
    asm volatile("" ::: "memory");                            \
    __builtin_amdgcn_s_barrier();                             \
    asm volatile("" ::: "memory");                            \
  } while (0)

// ---------------- fp32 -> bf16 elementwise convert ----------------
__global__ __launch_bounds__(256) void k_cvt_bf16(const float* __restrict__ in,
                                                  bf16* __restrict__ out, int n) {
  int i = (blockIdx.x * 256 + threadIdx.x) * 4;
  if (i >= n) return;
  float4 v = *(const float4*)(in + i);
  union { bf16 h[4]; ushort4 u; } r;
  r.h[0] = (bf16)v.x; r.h[1] = (bf16)v.y; r.h[2] = (bf16)v.z; r.h[3] = (bf16)v.w;
  *(ushort4*)(out + i) = r.u;
}

// ---------------- fused weight transposes: all 4 weights in ONE dispatch ----------------
// flat block id decodes {w_qkv 512x1536 -> 768 tiles | w_proj 512x512 -> 256 |
// w1 512x2048 -> 1024 | w2 2048x512 -> 1024}; each tile = 32x32 transpose+cvt.
__global__ __launch_bounds__(256) void k_wtrans(const float* __restrict__ w_qkv,
                                                const float* __restrict__ w_proj,
                                                const float* __restrict__ w1,
                                                const float* __restrict__ w2,
                                                bf16* __restrict__ wqkvT,
                                                bf16* __restrict__ wprojT,
                                                bf16* __restrict__ w1T,
                                                bf16* __restrict__ w2T) {
  __shared__ float t[32][33];
  const int bid = blockIdx.x;
  const float* src;
  bf16* dst;
  int K, N, n0, k0;
  if (bid < 768) {            // w_qkv: K=512, N=1536 (48 x 16 tiles)
    src = w_qkv; dst = wqkvT; K = 512; N = 1536;
    n0 = (bid % 48) * 32; k0 = (bid / 48) * 32;
  } else if (bid < 1024) {    // w_proj: 512x512 (16 x 16)
    int i = bid - 768;
    src = w_proj; dst = wprojT; K = 512; N = 512;
    n0 = (i % 16) * 32; k0 = (i / 16) * 32;
  } else if (bid < 2048) {    // w1: K=512, N=2048 (64 x 16)
    int i = bid - 1024;
    src = w1; dst = w1T; K = 512; N = 2048;
    n0 = (i % 64) * 32; k0 = (i / 64) * 32;
  } else {                    // w2: K=2048, N=512 (16 x 64)
    int i = bid - 2048;
    src = w2; dst = w2T; K = 2048; N = 512;
    n0 = (i % 16) * 32; k0 = (i / 16) * 32;
  }
  const int tx = threadIdx.x, ty = threadIdx.y;
#pragma unroll
  for (int j = 0; j < 32; j += 8)
    t[ty + j][tx] = src[(size_t)(k0 + ty + j) * N + n0 + tx];
  __syncthreads();
#pragma unroll
  for (int j = 0; j < 32; j += 8)
    dst[(size_t)(n0 + ty + j) * K + k0 + tx] = (bf16)t[tx][ty + j];
}

// ---------------- GEMM: C[M][N] = A[M][K](bf16) * BT[N][K]^T + bias ----------------
// BM x 128 tile, BK=64, 512 threads = 8 waves (2 wr x 4 wc). global_load_lds
// width-16 staging, double-buffered, XOR-swizzled b128 frag reads, ONE
// __syncthreads per K-step (R14 A/B: two-barrier counted-vmcnt hurts here).
// Epilogue bounces C through LDS for coalesced 16-B stores.
template <int BM, bool GELU, bool RESID, bool STORE_BF16>
__global__ __launch_bounds__(512, 4) void k_gemm(const bf16* __restrict__ A,
                                                 const bf16* __restrict__ BT,
                                                 const float* __restrict__ bias,
                                                 const float* __restrict__ resid,
                                                 void* __restrict__ Cout,
                                                 int M, int N, int K) {
  constexpr int MI = BM / 32;          // M-frags per wave (wave M-span = BM/2)
  constexpr int AROUNDS = BM / 64;     // 512-thr staging rounds for A
  constexpr size_t MAIN = (size_t)2 * (BM + 128) * 64 * 2;
  constexpr size_t CST = (size_t)BM * 136 * (STORE_BF16 ? 2 : 4);
  constexpr size_t SMEM = MAIN > CST ? MAIN : CST;
  __shared__ __align__(16) char smem[SMEM];
  bf16* Asb = (bf16*)smem;                     // [2][BM*64]
  bf16* Bsb = Asb + 2 * BM * 64;               // [2][128*64]

  const int m0 = blockIdx.y * BM, n0 = blockIdx.x * 128;
  const int tid = threadIdx.x, lane = tid & 63, wid = tid >> 6;
  const int wr = wid >> 2, wc = wid & 3;
  const int r16 = lane & 15, g = lane >> 4;
  const int lrow = lane >> 3;                  // 0..7 rows within a gload round
  const int sch = (lane & 7) ^ lrow;           // inverse-swizzled source chunk

  f32x4 acc[MI][2] = {};

  const int NT = K >> 6;
  auto stage = [&](int t, int buf) {
    const int k0 = t << 6;
#pragma unroll
    for (int i = 0; i < AROUNDS; i++) {
      int row = i * 64 + wid * 8 + lrow;
      gload16(A + (size_t)(m0 + row) * K + k0 + sch * 8,
              Asb + buf * BM * 64 + (i * 64 + wid * 8) * 64);
    }
#pragma unroll
    for (int i = 0; i < 2; i++) {
      int row = i * 64 + wid * 8 + lrow;
      gload16(BT + (size_t)(n0 + row) * K + k0 + sch * 8,
              Bsb + buf * 128 * 64 + (i * 64 + wid * 8) * 64);
    }
  };

  stage(0, 0);
  __syncthreads();

  for (int t = 0; t < NT; t++) {
    const int cur = t & 1;
    if (t + 1 < NT) stage(t + 1, cur ^ 1);
    const bf16* Ab = Asb + cur * BM * 64;
    const bf16* Bb = Bsb + cur * 128 * 64;
#pragma unroll
    for (int kk = 0; kk < 2; kk++) {
      bf16x8 af[MI], bfr[2];
#pragma unroll
      for (int mi = 0; mi < MI; mi++)
        af[mi] = *(const bf16x8*)(Ab + (wr * (BM / 2) + mi * 16 + r16) * 64 +
                                  (((kk * 4 + g) ^ (r16 & 7)) * 8));
#pragma unroll
      for (int ni = 0; ni < 2; ni++)
        bfr[ni] = *(const bf16x8*)(Bb + (wc * 32 + ni * 16 + r16) * 64 +
                                   (((kk * 4 + g) ^ (r16 & 7)) * 8));
#pragma unroll
      for (int mi = 0; mi < MI; mi++)
#pragma unroll
        for (int ni = 0; ni < 2; ni++)
          acc[mi][ni] = __builtin_amdgcn_mfma_f32_16x16x32_bf16(af[mi], bfr[ni],
                                                                acc[mi][ni], 0, 0, 0);
    }
    __syncthreads();
  }

  // ---- epilogue: acc -> LDS C-tile -> coalesced 16B stores ----
  float bv[2];
#pragma unroll
  for (int ni = 0; ni < 2; ni++) bv[ni] = bias[n0 + wc * 32 + ni * 16 + r16];

  if (STORE_BF16) {
    bf16* Cl = (bf16*)smem;
#pragma unroll
    for (int mi = 0; mi < MI; mi++)
#pragma unroll
      for (int ni = 0; ni < 2; ni++)
#pragma unroll
        for (int r = 0; r < 4; r++) {
          float v = acc[mi][ni][r] + bv[ni];
          if (GELU) v = 0.5f * v * (1.f + erff(v * 0.70710678118654752f));
          Cl[(wr * (BM / 2) + mi * 16 + 4 * g + r) * 136 + wc * 32 + ni * 16 + r16] =
              (bf16)v;
        }
    __syncthreads();
    constexpr int ROWS_PER = 512 * 8 / 128;  // 32
#pragma unroll
    for (int rr = 0; rr < BM / ROWS_PER; rr++) {
      int row = rr * ROWS_PER + (tid >> 4);
      int cc = (tid & 15) * 8;
      bf16x8 v = *(const bf16x8*)(Cl + row * 136 + cc);
      *(bf16x8*)((bf16*)Cout + (size_t)(m0 + row) * N + n0 + cc) = v;
    }
  } else {
    float* Cl = (float*)smem;
#pragma unroll
    for (int mi = 0; mi < MI; mi++)
#pragma unroll
      for (int ni = 0; ni < 2; ni++)
#pragma unroll
        for (int r = 0; r < 4; r++) {
          float v = acc[mi][ni][r] + bv[ni];
          if (GELU) v = 0.5f * v * (1.f + erff(v * 0.70710678118654752f));
          Cl[(wr * (BM / 2) + mi * 16 + 4 * g + r) * 136 + wc * 32 + ni * 16 + r16] = v;
        }
    __syncthreads();
    constexpr int ROWS_PER = 512 * 4 / 128;  // 16
#pragma unroll
    for (int rr = 0; rr < BM / ROWS_PER; rr++) {
      int row = rr * ROWS_PER + (tid >> 5);
      int cc = (tid & 31) * 4;
      f32x4 v = *(const f32x4*)(Cl + row * 136 + cc);
      if (RESID) {
        f32x4 rv = *(const f32x4*)(resid + (size_t)(m0 + row) * N + n0 + cc);
        v += rv;
      }
      *(f32x4*)((float*)Cout + (size_t)(m0 + row) * N + n0 + cc) = v;
    }
  }
}

// ---------------- V transpose+interleave: qkvb V-cols -> vt[B*H][64][Nq] ----------------
__global__ __launch_bounds__(256) void k_vtrans(const bf16* __restrict__ qkv,
                                                bf16* __restrict__ vt) {
  __shared__ bf16 T[64 * 66];
  const int kvb = blockIdx.x, bh = blockIdx.y;
  const int b = bh >> 3, h = bh & 7;
  const int tid = threadIdx.x, lane = tid & 63, w = tid >> 6;
  const bf16* src = qkv + ((size_t)b * Nq + kvb * 64) * (3 * Dq) + 2 * Dq + h * 64;
#pragma unroll
  for (int i = 0; i < 2; i++) {
    int u = tid + i * 256;
    int r = u >> 3, ch = u & 7;
    *(int4*)(&T[r * 66 + ch * 8]) = *(const int4*)(src + (size_t)r * (3 * Dq) + ch * 8);
  }
  __syncthreads();
  const int kvm = 16 * ((lane >> 2) & 3) + 4 * (lane >> 4) + (lane & 3);
  bf16* dst = vt + (size_t)bh * 64 * Nq + kvb * 64 + lane;
#pragma unroll
  for (int it = 0; it < 16; it++) {
    int e = w * 16 + it;
    dst[(size_t)e * Nq] = T[kvm * 66 + e];
  }
}

// ---------------- flash attention: O^T = V^T P^T, no-max exp2 softmax ----------------
// grid (B*H, Nq/64): 4 waves x 16 q-rows + counted-vmcnt two-barrier schedule
// (R14 A/B: helps attn; prefetch stays in flight through compute).
__global__ __launch_bounds__(256) void k_attn(const bf16* __restrict__ qkv,
                                              const bf16* __restrict__ vt,
                                              bf16* __restrict__ att) {
  __shared__ bf16 Ks[2][64 * 64];
  __shared__ bf16 Vs[2][64 * 64];
  const int qt = blockIdx.y, b = blockIdx.x >> 3, h = blockIdx.x & 7;
  const int tid = threadIdx.x, lane = tid & 63, wid = tid >> 6;
  const int r16 = lane & 15, g = lane >> 4;
  const size_t base = (size_t)b * Nq * (3 * Dq);
  const bf16* qp = qkv + base + h * 64;
  const bf16* kp = qkv + base + Dq + h * 64;
  const bf16* vtp = vt + (size_t)(b * HEADS + h) * 64 * Nq;
  const int q0 = qt * 64 + wid * 16;

  // Q frags, pre-scaled by log2(e) -> S in exp2 domain
  bf16x8 qf[2];
#pragma unroll
  for (int kk = 0; kk < 2; kk++) {
    bf16x8 q = *(const bf16x8*)(qp + (size_t)(q0 + r16) * (3 * Dq) + kk * 32 + g * 8);
#pragma unroll
    for (int j = 0; j < 8; j++) q[j] = (bf16)((float)q[j] * 1.44269504f);
    qf[kk] = q;
  }

  const int srow = lane >> 3;
  const int sch = (lane & 7) ^ srow;
  const bf16x4 ones = {(bf16)1.f, (bf16)1.f, (bf16)1.f, (bf16)1.f};

  f32x4 o[4] = {};
  f32x4 ol = {};              // l accumulator (every row = sum over kv of P)

#pragma unroll
  for (int i = 0; i < 2; i++) {
    int br = (wid * 2 + i) * 8;
    gload16(kp + (size_t)(br + srow) * (3 * Dq) + sch * 8, &Ks[0][br * 64]);
    gload16(vtp + (size_t)(br + srow) * Nq + sch * 8, &Vs[0][br * 64]);
  }
  __syncthreads();  // drains Q loads + stage(0)

  const int NTILES = Nq / 64;
  auto tile = [&](int t, int c) {
    if (t + 1 < NTILES) {
      const int kv1 = (t + 1) * 64;
#pragma unroll
      for (int i = 0; i < 2; i++) {
        int br = (wid * 2 + i) * 8;
        gload16(kp + (size_t)(kv1 + br + srow) * (3 * Dq) + sch * 8,
                &Ks[c ^ 1][br * 64]);
        gload16(vtp + (size_t)(br + srow) * Nq + kv1 + sch * 8, &Vs[c ^ 1][br * 64]);
      }
      VM_BARRIER(4);
    } else {
      VM_BARRIER(0);
    }

    // S^T[kv][q]: s[nt]
    f32x4 s[4] = {};
#pragma unroll
    for (int kk = 0; kk < 2; kk++)
#pragma unroll
      for (int nt = 0; nt < 4; nt++) {
        const bf16x8 kf = *(const bf16x8*)(
            &Ks[c][(nt * 16 + r16) * 64 + (((4 * kk + g) ^ (r16 & 7)) * 8)]);
        s[nt] = __builtin_amdgcn_mfma_f32_16x16x32_bf16(kf, qf[kk], s[nt], 0, 0, 0);
      }

    // no-max softmax: P = 2^s directly (range-safe; O/l cancels the constant)
#pragma unroll
    for (int nt = 0; nt < 4; nt++)
#pragma unroll
      for (int r = 0; r < 4; r++) s[nt][r] = fexp2(s[nt][r]);

    // pack P^T to bf16: pk[s4] IS the 16x16x16 B-frag (k=4g+j, col=r16)
    bf16x4 pk[4];
#pragma unroll
    for (int s4 = 0; s4 < 4; s4++) {
      bf16x4 p;
#pragma unroll
      for (int j = 0; j < 4; j++) p[j] = (bf16)s[s4][j];
      pk[s4] = p;
    }

    // l via MFMA: every row of ol += column-sums of this tile's P
    ol = mfma16(ones, pk[0], ol);
    ol = mfma16(ones, pk[1], ol);
    ol = mfma16(ones, pk[2], ol);
    ol = mfma16(ones, pk[3], ol);

    // PV: O^T[e][q] += V^T A-frags x P^T B-frags, 4 steps of k=16
#pragma unroll
    for (int ot = 0; ot < 4; ot++) {
      const int row = ot * 16 + r16;
      const bf16x8 vf0 = *(const bf16x8*)(
          &Vs[c][row * 64 + (((2 * g + 0) ^ (r16 & 7)) * 8)]);
      const bf16x8 vf1 = *(const bf16x8*)(
          &Vs[c][row * 64 + (((2 * g + 1) ^ (r16 & 7)) * 8)]);
      const bf16x4 a0 = __builtin_shufflevector(vf0, vf0, 0, 1, 2, 3);
      const bf16x4 a1 = __builtin_shufflevector(vf0, vf0, 4, 5, 6, 7);
      const bf16x4 a2 = __builtin_shufflevector(vf1, vf1, 0, 1, 2, 3);
      const bf16x4 a3 = __builtin_shufflevector(vf1, vf1, 4, 5, 6, 7);
      o[ot] = mfma16(a0, pk[0], o[ot]);
      o[ot] = mfma16(a1, pk[1], o[ot]);
      o[ot] = mfma16(a2, pk[2], o[ot]);
      o[ot] = mfma16(a3, pk[3], o[ot]);
    }
    END_BARRIER();
  };

  for (int t = 0; t < NTILES; t += 2) {
    tile(t, 0);
    tile(t + 1, 1);
  }

  asm volatile("s_nop 7\ns_nop 7");  // MFMA->VALU hazard guard before epilogue

  // epilogue: O^T col=q=r16 (same lane as l), row e = ot*16+4g+r
  const float li = 0.125f / ol[0];
  const size_t rowoff = ((size_t)b * Nq + q0 + r16) * Dq + h * 64;
#pragma unroll
  for (int ot = 0; ot < 4; ot++) {
    union { bf16 h[4]; ushort4 u; } r4;
#pragma unroll
    for (int r = 0; r < 4; r++) r4.h[r] = (bf16)(o[ot][r] * li);
    *(ushort4*)(att + rowoff + ot * 16 + 4 * g) = r4.u;
  }
}

// ---------------- LayerNorm over D=512, one wave per row ----------------
template <bool WB>
__global__ __launch_bounds__(64) void k_ln(const float* __restrict__ in,
                                           const float* __restrict__ gamma,
                                           const float* __restrict__ beta,
                                           float* __restrict__ outf,
                                           bf16* __restrict__ outb) {
  const int row = blockIdx.x, lane = threadIdx.x;
  const float* p = in + (size_t)row * Dq + lane * 8;
  float4 a = *(const float4*)p;
  float4 c = *(const float4*)(p + 4);
  float vals[8] = {a.x, a.y, a.z, a.w, c.x, c.y, c.z, c.w};
  float s = 0.f, q = 0.f;
#pragma unroll
  for (int j = 0; j < 8; j++) { s += vals[j]; q += vals[j] * vals[j]; }
#pragma unroll
  for (int off = 1; off < 64; off <<= 1) {
    s += __shfl_xor(s, off);
    q += __shfl_xor(q, off);
  }
  float mean = s * (1.f / Dq);
  float var = q * (1.f / Dq) - mean * mean;
  float rstd = rsqrtf(var + 1e-5f);
  float of[8];
#pragma unroll
  for (int j = 0; j < 8; j++) {
    int col = lane * 8 + j;
    of[j] = (vals[j] - mean) * rstd * gamma[col] + beta[col];
  }
  float4* op = (float4*)(outf + (size_t)row * Dq + lane * 8);
  op[0] = make_float4(of[0], of[1], of[2], of[3]);
  op[1] = make_float4(of[4], of[5], of[6], of[7]);
  if (WB) {
    union { bf16 h[8]; ushort4 u[2]; } rr;
#pragma unroll
    for (int j = 0; j < 8; j++) rr.h[j] = (bf16)of[j];
    ushort4* ob = (ushort4*)(outb + (size_t)row * Dq + lane * 8);
    ob[0] = rr.u[0];
    ob[1] = rr.u[1];
  }
}

extern "C" void kernel_launch(void* const* d_in, const int* in_sizes, int n_in,
                              void* d_out, int out_size, void* d_ws, size_t ws_size,
                              hipStream_t stream) {
  const float* x      = (const float*)d_in[0];
  const float* w_qkv  = (const float*)d_in[1];
  const float* b_qkv  = (const float*)d_in[2];
  const float* w_proj = (const float*)d_in[3];
  const float* b_proj = (const float*)d_in[4];
  const float* ln1_g  = (const float*)d_in[5];
  const float* ln1_b  = (const float*)d_in[6];
  const float* w1     = (const float*)d_in[7];
  const float* b1     = (const float*)d_in[8];
  const float* w2     = (const float*)d_in[9];
  const float* b2     = (const float*)d_in[10];
  const float* ln2_g  = (const float*)d_in[11];
  const float* ln2_b  = (const float*)d_in[12];
  float* out = (float*)d_out;

  const int M = Bq * Nq;  // 8192 rows

  char* p = (char*)d_ws;
  auto alloc = [&](size_t bytes) -> void* {
    char* r = p;
    p += (bytes + 255) & ~(size_t)255;
    return (void*)r;
  };
  bf16* xb     = (bf16*)alloc((size_t)M * Dq * 2);        // x bf16; later reused as att
  bf16* qkvb   = (bf16*)alloc((size_t)M * 3 * Dq * 2);
  bf16* wqkvT  = (bf16*)alloc((size_t)3 * Dq * Dq * 2);
  bf16* wprojT = (bf16*)alloc((size_t)Dq * Dq * 2);
  bf16* w1T    = (bf16*)alloc((size_t)Hq * Dq * 2);
  bf16* w2T    = (bf16*)alloc((size_t)Dq * Hq * 2);
  float* y1    = (float*)alloc((size_t)M * Dq * 4);       // also y2
  float* x1f   = (float*)alloc((size_t)M * Dq * 4);
  bf16* x1b    = (bf16*)alloc((size_t)M * Dq * 2);
  bf16* hb     = (bf16*)alloc((size_t)M * Hq * 2);
  bf16* attb   = xb;   // alias: xb consumed by qkv GEMM before attention writes
  bf16* vtb    = hb;   // alias: hb written by ffn1 only after attention is done

  dim3 tb(32, 8);
  k_cvt_bf16<<<(M * Dq / 4 + 255) / 256, 256, 0, stream>>>(x, xb, M * Dq);
  // all 4 weight transposes fused into one dispatch (3072 tiles)
  k_wtrans<<<3072, tb, 0, stream>>>(w_qkv, w_proj, w1, w2, wqkvT, wprojT, w1T, w2T);

  // qkv = x @ w_qkv + b_qkv
  k_gemm<128, false, false, true><<<dim3((3 * Dq) / 128, M / 128), 512, 0, stream>>>(
      xb, wqkvT, b_qkv, nullptr, qkvb, M, 3 * Dq, Dq);
  // vt = transpose+interleave of V part
  k_vtrans<<<dim3(Nq / 64, Bq * HEADS), 256, 0, stream>>>(qkvb, vtb);
  // attention (QBLK=64: 1024 blocks, 4 blocks/CU)
  k_attn<<<dim3(Bq * HEADS, Nq / 64), 256, 0, stream>>>(qkvb, vtb, attb);
  // y1 = att @ w_proj + b_proj + x
  k_gemm<64, false, true, false><<<dim3(Dq / 128, M / 64), 512, 0, stream>>>(
      attb, wprojT, b_proj, x, y1, M, Dq, Dq);
  // x1 = LN1(y1) -> fp32 + bf16
  k_ln<true><<<M, 64, 0, stream>>>(y1, ln1_g, ln1_b, x1f, x1b);
  // h = gelu(x1 @ w1 + b1)
  k_gemm<128, true, false, true><<<dim3(Hq / 128, M / 128), 512, 0, stream>>>(
      x1b, w1T, b1, nullptr, hb, M, Hq, Dq);
  // y2 = h @ w2 + b2 + x1
  k_gemm<64, false, true, false><<<dim3(Dq / 128, M / 64), 512, 0, stream>>>(
      hb, w2T, b2, x1f, y1, M, Dq, Hq);
  // out = LN2(y2)
  k_ln<false><<<M, 64, 0, stream>>>(y1, ln2_g, ln2_b, out, nullptr);
}